// Round 1
// baseline (11997.781 us; speedup 1.0000x reference)
//
#include <hip/hip_runtime.h>
#include <math.h>

#define B 8
#define N 4096
#define D 256
#define H 8
#define DH 32
#define M 256
#define DEPTH 4
#define HID 1024
#define NRM 0.4204482076268573f   // 32^-0.25

// ---------------- h = x + pos ----------------
__global__ void add_pos_kernel(const float* __restrict__ x, const float* __restrict__ pos,
                               float* __restrict__ h) {
    int i = blockIdx.x * 256 + threadIdx.x;     // grid sized exactly B*N*D/256
    int nd = i % (N * D);
    h[i] = x[i] + pos[nd];
}

// ---------------- LayerNorm: 1 wave per row (D=256, float4) ----------------
__global__ __launch_bounds__(256) void ln_kernel(const float* __restrict__ in,
                                                 const float* __restrict__ g,
                                                 const float* __restrict__ bb,
                                                 float* __restrict__ out) {
    int wave = threadIdx.x >> 6, lane = threadIdx.x & 63;
    long row = (long)blockIdx.x * 4 + wave;     // B*N rows
    const float4* rp = reinterpret_cast<const float4*>(in + row * D);
    float4 v = rp[lane];
    float s = v.x + v.y + v.z + v.w;
#pragma unroll
    for (int o = 32; o >= 1; o >>= 1) s += __shfl_xor(s, o);
    float mu = s * (1.0f / D);
    float d0 = v.x - mu, d1 = v.y - mu, d2 = v.z - mu, d3 = v.w - mu;
    float ss = d0 * d0 + d1 * d1 + d2 * d2 + d3 * d3;
#pragma unroll
    for (int o = 32; o >= 1; o >>= 1) ss += __shfl_xor(ss, o);
    float inv = rsqrtf(ss * (1.0f / D) + 1e-6f);
    float4 gv = reinterpret_cast<const float4*>(g)[lane];
    float4 bv = reinterpret_cast<const float4*>(bb)[lane];
    float4 o4;
    o4.x = d0 * inv * gv.x + bv.x;
    o4.y = d1 * inv * gv.y + bv.y;
    o4.z = d2 * inv * gv.z + bv.z;
    o4.w = d3 * inv * gv.w + bv.w;
    reinterpret_cast<float4*>(out + row * D)[lane] = o4;
}

// ---------------- generic fp32 GEMM: C(=A@B [+bias][gelu][+=]) ----------------
// A: Mr x K row-major, Bw: K x Nc row-major, C: Mr x Nc. 64x64 tile, BK=16.
template <bool BIAS, bool GELU_ACT, bool RESID>
__global__ __launch_bounds__(256) void gemm_kernel(const float* __restrict__ A,
                                                   const float* __restrict__ Bw,
                                                   const float* __restrict__ bias,
                                                   float* __restrict__ C,
                                                   int K, int Nc) {
    __shared__ float As[16][64];
    __shared__ float Bs[16][64];
    int t = threadIdx.x;
    int tx = t & 15, ty = t >> 4;
    long m0 = (long)blockIdx.y * 64;
    int n0 = blockIdx.x * 64;
    float acc[4][4] = {};
    for (int k0 = 0; k0 < K; k0 += 16) {
#pragma unroll
        for (int i = 0; i < 4; i++) {
            int idx = t + i * 256;
            int am = idx >> 4, ak = idx & 15;
            As[ak][am] = A[(m0 + am) * K + k0 + ak];
            int bk = idx >> 6, bn = idx & 63;
            Bs[bk][bn] = Bw[(long)(k0 + bk) * Nc + n0 + bn];
        }
        __syncthreads();
#pragma unroll
        for (int k = 0; k < 16; k++) {
            float a[4], b[4];
#pragma unroll
            for (int i = 0; i < 4; i++) a[i] = As[k][ty * 4 + i];
#pragma unroll
            for (int i = 0; i < 4; i++) b[i] = Bs[k][tx * 4 + i];
#pragma unroll
            for (int i = 0; i < 4; i++)
#pragma unroll
                for (int j = 0; j < 4; j++) acc[i][j] += a[i] * b[j];
        }
        __syncthreads();
    }
#pragma unroll
    for (int i = 0; i < 4; i++) {
        long row = m0 + ty * 4 + i;
#pragma unroll
        for (int j = 0; j < 4; j++) {
            int col = n0 + tx * 4 + j;
            float v = acc[i][j];
            if (BIAS) v += bias[col];
            if (GELU_ACT) v = 0.5f * v * (1.0f + erff(v * 0.70710678118654752f));
            if (RESID)
                C[row * Nc + col] += v;
            else
                C[row * Nc + col] = v;
        }
    }
}

// ---------------- k-side: partial max of u over (n,m) per (b,h) ----------------
__global__ __launch_bounds__(256) void kmax_part_kernel(const float* __restrict__ qkv,
                                                        const float* __restrict__ proj,
                                                        float* __restrict__ part) {
    __shared__ float projL[M][33];
    __shared__ float ktd[DH];
    __shared__ float red[4];
    int t = threadIdx.x;
    int bh = blockIdx.x, b = bh >> 3, h = bh & 7;
    for (int i = t; i < M * DH; i += 256) { int m = i >> 5, d = i & 31; projL[m][d] = proj[i]; }
    float lmax = -1e30f;
    int n0 = blockIdx.y * (N / 16);
    for (int n = n0; n < n0 + N / 16; n++) {
        __syncthreads();
        if (t < DH) ktd[t] = qkv[((long)(b * N + n)) * (3 * D) + D + h * DH + t] * NRM;
        __syncthreads();
        float u = 0.f;
#pragma unroll
        for (int d = 0; d < DH; d++) u += ktd[d] * projL[t][d];
        lmax = fmaxf(lmax, u);
    }
#pragma unroll
    for (int o = 32; o >= 1; o >>= 1) lmax = fmaxf(lmax, __shfl_xor(lmax, o));
    if ((t & 63) == 0) red[t >> 6] = lmax;
    __syncthreads();
    if (t == 0) part[bh * 16 + blockIdx.y] = fmaxf(fmaxf(red[0], red[1]), fmaxf(red[2], red[3]));
}

__global__ void kmax_reduce_kernel(const float* __restrict__ part, float* __restrict__ kmax) {
    int bh = threadIdx.x;   // 64 threads
    float m = -1e30f;
    for (int i = 0; i < 16; i++) m = fmaxf(m, part[bh * 16 + i]);
    kmax[bh] = m;
}

__global__ void zero_kernel(float* __restrict__ p, int n) {
    int i = blockIdx.x * 256 + threadIdx.x;
    if (i < n) p[i] = 0.f;
}

// ---------------- k-side: kv[m][d] and ksum[m] accumulation ----------------
__global__ __launch_bounds__(256) void kv_kernel(const float* __restrict__ qkv,
                                                 const float* __restrict__ proj,
                                                 const float* __restrict__ kmax,
                                                 float* __restrict__ kv,
                                                 float* __restrict__ ksum) {
    __shared__ float projL[M][33];
    __shared__ float ktd[DH];
    __shared__ float vrow[DH];
    int t = threadIdx.x;
    int bh = blockIdx.x, b = bh >> 3, h = bh & 7;
    for (int i = t; i < M * DH; i += 256) { int m = i >> 5, d = i & 31; projL[m][d] = proj[i]; }
    float km = kmax[bh];
    float acc[DH];
#pragma unroll
    for (int d = 0; d < DH; d++) acc[d] = 0.f;
    float asum = 0.f;
    int n0 = blockIdx.y * (N / 16);
    for (int n = n0; n < n0 + N / 16; n++) {
        __syncthreads();
        if (t < DH) {
            long base = ((long)(b * N + n)) * (3 * D);
            ktd[t] = qkv[base + D + h * DH + t] * NRM;
            vrow[t] = qkv[base + 2 * D + h * DH + t];
        }
        __syncthreads();
        float u = 0.f, dg = 0.f;
#pragma unroll
        for (int d = 0; d < DH; d++) {
            float kd = ktd[d];
            u += kd * projL[t][d];
            dg += kd * kd;
        }
        float kp = (expf(u - 0.5f * dg - km) + 1e-4f) * 0.0625f;
        asum += kp;
#pragma unroll
        for (int d = 0; d < DH; d++) acc[d] += kp * vrow[d];
    }
    float* kvb = kv + (long)bh * M * DH;
#pragma unroll
    for (int d = 0; d < DH; d++) atomicAdd(&kvb[t * DH + d], acc[d]);
    atomicAdd(&ksum[bh * M + t], asum);
}

// ---------------- q-side fused: qp, z, out = z * qp@kv (merged-head layout) ----------------
__global__ __launch_bounds__(256) void attn_kernel(const float* __restrict__ qkv,
                                                   const float* __restrict__ proj,
                                                   const float* __restrict__ kv,
                                                   const float* __restrict__ ksum,
                                                   float* __restrict__ attn) {
    __shared__ float qt[32][33];
    __shared__ float qp[32][260];
    __shared__ float zrow[32];
    int t = threadIdx.x;
    int bh = blockIdx.x, b = bh >> 3, h = bh & 7;
    int n0 = blockIdx.y * 32;
    for (int i = t; i < 32 * 32; i += 256) {
        int r = i >> 5, d = i & 31;
        qt[r][d] = qkv[((long)(b * N + n0 + r)) * (3 * D) + h * DH + d] * NRM;
    }
    __syncthreads();
    int r = t >> 3, mg = t & 7;
    const float* kvp = kv + (long)bh * M * DH;
    const float* ksp = ksum + bh * M;
    float dg = 0.f;
#pragma unroll
    for (int d = 0; d < DH; d++) { float x = qt[r][d]; dg += x * x; }
    dg *= 0.5f;
    float uv[32];
    float umax = -1e30f;
#pragma unroll 4
    for (int j = 0; j < 32; j++) {
        int m = mg + (j << 3);
        float u = 0.f;
#pragma unroll
        for (int d = 0; d < DH; d++) u += qt[r][d] * proj[m * DH + d];
        uv[j] = u;
        umax = fmaxf(umax, u);
    }
    umax = fmaxf(umax, __shfl_xor(umax, 1));
    umax = fmaxf(umax, __shfl_xor(umax, 2));
    umax = fmaxf(umax, __shfl_xor(umax, 4));
    float zs = 0.f;
#pragma unroll 4
    for (int j = 0; j < 32; j++) {
        int m = mg + (j << 3);
        float p = (expf(uv[j] - dg - umax) + 1e-4f) * 0.0625f;
        qp[r][m] = p;
        zs += p * ksp[m];
    }
    zs += __shfl_xor(zs, 1);
    zs += __shfl_xor(zs, 2);
    zs += __shfl_xor(zs, 4);
    if (mg == 0) zrow[r] = 1.0f / (zs + 1e-6f);
    __syncthreads();
    int r2 = t >> 3, dd0 = (t & 7) << 2;
    float o0 = 0.f, o1 = 0.f, o2 = 0.f, o3 = 0.f;
#pragma unroll 8
    for (int m = 0; m < M; m++) {
        float p = qp[r2][m];
        const float* kr = kvp + m * DH + dd0;
        o0 += p * kr[0];
        o1 += p * kr[1];
        o2 += p * kr[2];
        o3 += p * kr[3];
    }
    float z = zrow[r2];
    long ob = ((long)(b * N + n0 + r2)) * D + h * DH + dd0;
    attn[ob + 0] = o0 * z;
    attn[ob + 1] = o1 * z;
    attn[ob + 2] = o2 * z;
    attn[ob + 3] = o3 * z;
}

extern "C" void kernel_launch(void* const* d_in, const int* in_sizes, int n_in,
                              void* d_out, int out_size, void* d_ws, size_t ws_size,
                              hipStream_t stream) {
    const float* x = (const float*)d_in[0];
    const float* pos = (const float*)d_in[1];
    const float* g1 = (const float*)d_in[2];
    const float* b1 = (const float*)d_in[3];
    const float* g2 = (const float*)d_in[4];
    const float* b2 = (const float*)d_in[5];
    const float* Wqkv = (const float*)d_in[6];
    const float* Wproj = (const float*)d_in[7];
    const float* bproj = (const float*)d_in[8];
    const float* W1 = (const float*)d_in[9];
    const float* b1m = (const float*)d_in[10];
    const float* W2 = (const float*)d_in[11];
    const float* b2m = (const float*)d_in[12];
    const float* projm = (const float*)d_in[13];

    float* h = (float*)d_out;
    float* ws = (float*)d_ws;
    float* ln = ws;                                  // B*N*D      = 8M
    float* qkv = ln + (size_t)B * N * D;             // B*N*3D     = 24M
    float* attn = qkv + (size_t)B * N * 3 * D;       // B*N*D      = 8M
    float* hid = qkv;                                // aliases qkv+attn (32M) — both dead by MLP
    float* kvb = attn + (size_t)B * N * D;           // B*H*M*DH   = 512K
    float* ksum = kvb + (size_t)B * H * M * DH;      // B*H*M      = 16K
    float* kpart = ksum + (size_t)B * H * M;         // B*H*16
    float* kmaxb = kpart + (size_t)B * H * 16;       // B*H

    add_pos_kernel<<<B * N * D / 256, 256, 0, stream>>>(x, pos, h);

    for (int l = 0; l < DEPTH; l++) {
        const float* Wq = Wqkv + (size_t)l * D * 3 * D;
        const float* Wp = Wproj + (size_t)l * D * D;
        const float* bp = bproj + (size_t)l * D;
        const float* W1l = W1 + (size_t)l * D * HID;
        const float* b1l = b1m + (size_t)l * HID;
        const float* W2l = W2 + (size_t)l * HID * D;
        const float* b2l = b2m + (size_t)l * D;
        const float* prl = projm + (size_t)l * M * DH;

        ln_kernel<<<B * N / 4, 256, 0, stream>>>(h, g1, b1, ln);
        gemm_kernel<false, false, false><<<dim3(3 * D / 64, B * N / 64), 256, 0, stream>>>(
            ln, Wq, nullptr, qkv, D, 3 * D);
        kmax_part_kernel<<<dim3(B * H, 16), 256, 0, stream>>>(qkv, prl, kpart);
        kmax_reduce_kernel<<<1, 64, 0, stream>>>(kpart, kmaxb);
        zero_kernel<<<(B * H * M * DH + B * H * M + 255) / 256, 256, 0, stream>>>(
            kvb, B * H * M * DH + B * H * M);
        kv_kernel<<<dim3(B * H, 16), 256, 0, stream>>>(qkv, prl, kmaxb, kvb, ksum);
        attn_kernel<<<dim3(B * H, N / 32), 256, 0, stream>>>(qkv, prl, kvb, ksum, attn);
        gemm_kernel<true, false, true><<<dim3(D / 64, B * N / 64), 256, 0, stream>>>(
            attn, Wp, bp, h, D, D);
        ln_kernel<<<B * N / 4, 256, 0, stream>>>(h, g2, b2, ln);
        gemm_kernel<true, true, false><<<dim3(HID / 64, B * N / 64), 256, 0, stream>>>(
            ln, W1l, b1l, hid, D, HID);
        gemm_kernel<true, false, true><<<dim3(D / 64, B * N / 64), 256, 0, stream>>>(
            hid, W2l, b2l, h, HID, D);
    }
}

// Round 2
// 2742.045 us; speedup vs baseline: 4.3755x; 4.3755x over previous
//
#include <hip/hip_runtime.h>
#include <hip/hip_bf16.h>
#include <math.h>

#define B 8
#define N 4096
#define D 256
#define H 8
#define DH 32
#define M 256
#define DEPTH 4
#define HID 1024
#define NRM 0.4204482076268573f   // 32^-0.25

typedef __attribute__((ext_vector_type(8))) short short8;
typedef __attribute__((ext_vector_type(4))) float f32x4;
typedef unsigned short ushort_t;

static __device__ __forceinline__ unsigned short f2bf(float f) {
    __hip_bfloat16 h = __float2bfloat16(f);
    return __builtin_bit_cast(unsigned short, h);
}
static __device__ __forceinline__ float bf2f(unsigned short u) {
    __hip_bfloat16 h = __builtin_bit_cast(__hip_bfloat16, u);
    return __bfloat162float(h);
}

// ---------------- h = x + pos ----------------
__global__ void add_pos_kernel(const float* __restrict__ x, const float* __restrict__ pos,
                               float* __restrict__ h) {
    int i = blockIdx.x * 256 + threadIdx.x;
    int nd = i % (N * D);
    h[i] = x[i] + pos[nd];
}

// ---------------- weight fp32 (K x N) -> bf16 transposed (N x K) ----------------
__global__ __launch_bounds__(256) void wtrans_kernel(const float* __restrict__ in,
                                                     unsigned short* __restrict__ out,
                                                     int Kd, int Nd) {
    __shared__ float tl[32][33];
    int n0 = blockIdx.x * 32, k0 = blockIdx.y * 32;
    int t = threadIdx.x;
    int kk = t >> 3, c4 = (t & 7) * 4;
    float4 v = *reinterpret_cast<const float4*>(&in[(size_t)(k0 + kk) * Nd + n0 + c4]);
    tl[kk][c4 + 0] = v.x; tl[kk][c4 + 1] = v.y; tl[kk][c4 + 2] = v.z; tl[kk][c4 + 3] = v.w;
    __syncthreads();
    int nn = t >> 3, k4 = (t & 7) * 4;
    ushort4 o;
    o.x = f2bf(tl[k4 + 0][nn]); o.y = f2bf(tl[k4 + 1][nn]);
    o.z = f2bf(tl[k4 + 2][nn]); o.w = f2bf(tl[k4 + 3][nn]);
    *reinterpret_cast<ushort4*>(&out[(size_t)(n0 + nn) * Kd + k0 + k4]) = o;
}

// ---------------- LayerNorm -> bf16 ----------------
__global__ __launch_bounds__(256) void ln_kernel(const float* __restrict__ in,
                                                 const float* __restrict__ g,
                                                 const float* __restrict__ bb,
                                                 unsigned short* __restrict__ out) {
    int wave = threadIdx.x >> 6, lane = threadIdx.x & 63;
    long row = (long)blockIdx.x * 4 + wave;
    float4 v = reinterpret_cast<const float4*>(in + row * D)[lane];
    float s = v.x + v.y + v.z + v.w;
#pragma unroll
    for (int o = 32; o >= 1; o >>= 1) s += __shfl_xor(s, o);
    float mu = s * (1.0f / D);
    float d0 = v.x - mu, d1 = v.y - mu, d2 = v.z - mu, d3 = v.w - mu;
    float ss = d0 * d0 + d1 * d1 + d2 * d2 + d3 * d3;
#pragma unroll
    for (int o = 32; o >= 1; o >>= 1) ss += __shfl_xor(ss, o);
    float inv = rsqrtf(ss * (1.0f / D) + 1e-6f);
    float4 gv = reinterpret_cast<const float4*>(g)[lane];
    float4 bv = reinterpret_cast<const float4*>(bb)[lane];
    ushort4 o4;
    o4.x = f2bf(d0 * inv * gv.x + bv.x);
    o4.y = f2bf(d1 * inv * gv.y + bv.y);
    o4.z = f2bf(d2 * inv * gv.z + bv.z);
    o4.w = f2bf(d3 * inv * gv.w + bv.w);
    *reinterpret_cast<ushort4*>(&out[row * D + lane * 4]) = o4;
}

// ---------------- bf16 MFMA GEMM: C = A(MxK) @ Bt(NxK)^T ----------------
// 128x128 tile, BK=32, 4 waves 2x2 each owning 64x64 (4x4 frags of 16x16x32).
template <bool BIAS, bool GELU_ACT, bool RESID, bool OUT16>
__global__ __launch_bounds__(256) void mgemm_kernel(const unsigned short* __restrict__ A,
                                                    const unsigned short* __restrict__ Bt,
                                                    const float* __restrict__ bias,
                                                    float* __restrict__ C,
                                                    unsigned short* __restrict__ O16,
                                                    int K, int Nc) {
    __shared__ short Als[128][32];
    __shared__ short Bls[128][32];
    int t = threadIdx.x;
    int l = t & 63, w = t >> 6;
    int wr = w >> 1, wc = w & 1;
    long m0 = (long)blockIdx.y * 128;
    int n0 = blockIdx.x * 128;
    int lr = l & 15;
    int kp8 = (l >> 4) * 8;
    int srow = t >> 2, skoff = (t & 3) * 8;

    f32x4 acc[4][4];
#pragma unroll
    for (int i = 0; i < 4; i++)
#pragma unroll
        for (int j = 0; j < 4; j++) acc[i][j] = (f32x4){0.f, 0.f, 0.f, 0.f};

    for (int k0 = 0; k0 < K; k0 += 32) {
#pragma unroll
        for (int it = 0; it < 2; it++) {
            int r = srow + it * 64;
            short8 va = *reinterpret_cast<const short8*>(&A[(size_t)(m0 + r) * K + k0 + skoff]);
            *reinterpret_cast<short8*>(&Als[r][skoff]) = va;
            short8 vb = *reinterpret_cast<const short8*>(&Bt[(size_t)(n0 + r) * K + k0 + skoff]);
            *reinterpret_cast<short8*>(&Bls[r][skoff]) = vb;
        }
        __syncthreads();
        short8 a[4], b[4];
#pragma unroll
        for (int i = 0; i < 4; i++)
            a[i] = *reinterpret_cast<const short8*>(&Als[wr * 64 + i * 16 + lr][kp8]);
#pragma unroll
        for (int j = 0; j < 4; j++)
            b[j] = *reinterpret_cast<const short8*>(&Bls[wc * 64 + j * 16 + lr][kp8]);
#pragma unroll
        for (int i = 0; i < 4; i++)
#pragma unroll
            for (int j = 0; j < 4; j++)
                acc[i][j] = __builtin_amdgcn_mfma_f32_16x16x32_bf16(a[i], b[j], acc[i][j], 0, 0, 0);
        __syncthreads();
    }

    int rif = (l >> 4) * 4;
#pragma unroll
    for (int i = 0; i < 4; i++) {
#pragma unroll
        for (int j = 0; j < 4; j++) {
            int gcol = n0 + wc * 64 + j * 16 + lr;
            float bv = BIAS ? bias[gcol] : 0.f;
#pragma unroll
            for (int r = 0; r < 4; r++) {
                long grow = m0 + wr * 64 + i * 16 + rif + r;
                float v = acc[i][j][r] + bv;
                if (GELU_ACT) v = 0.5f * v * (1.0f + erff(v * 0.70710678118654752f));
                if (OUT16) {
                    O16[grow * Nc + gcol] = f2bf(v);
                } else if (RESID) {
                    C[grow * Nc + gcol] += v;
                } else {
                    C[grow * Nc + gcol] = v;
                }
            }
        }
    }
}

// ---------------- kv: online-max partials, no atomics ----------------
// grid (B*H, P=8); block handles N/8=512 rows in 16 chunks of 32.
// thread t owns feature m=t; proj row in registers.
#define KV_P 8
#define KV_ROWS (N / KV_P)      // 512
#define PSZ 8484                // 8192 acc + 256 asum + 32 vsum + 1 Lm + pad
__global__ __launch_bounds__(256) void kv_kernel(const float* __restrict__ qkv,
                                                 const float* __restrict__ proj,
                                                 float* __restrict__ kvp) {
    __shared__ float Kl[32][36];
    __shared__ float Vl[32][36];
    __shared__ float dgl[32];
    __shared__ float red[4];
    __shared__ float vred[256][4];
    int t = threadIdx.x;
    int l = t & 63, w = t >> 6;
    int bh = blockIdx.x, b = bh >> 3, h = bh & 7;
    int n0 = blockIdx.y * KV_ROWS;

    float4 pr[8];
#pragma unroll
    for (int d4 = 0; d4 < 8; d4++)
        pr[d4] = *reinterpret_cast<const float4*>(&proj[t * DH + d4 * 4]);

    float4 av[8];
#pragma unroll
    for (int d4 = 0; d4 < 8; d4++) av[d4] = (float4){0.f, 0.f, 0.f, 0.f};
    float asum = 0.f, Lm = -1e30f;
    float4 vs4 = (float4){0.f, 0.f, 0.f, 0.f};

    int nl = t >> 3, fo = (t & 7) * 4;
    for (int c = 0; c < KV_ROWS / 32; c++) {
        __syncthreads();
        size_t rbase = ((size_t)(b * N + n0 + c * 32 + nl)) * (3 * D);
        float4 kf = *reinterpret_cast<const float4*>(&qkv[rbase + D + h * DH + fo]);
        float4 vf = *reinterpret_cast<const float4*>(&qkv[rbase + 2 * D + h * DH + fo]);
        kf.x *= NRM; kf.y *= NRM; kf.z *= NRM; kf.w *= NRM;
        Kl[nl][fo + 0] = kf.x; Kl[nl][fo + 1] = kf.y; Kl[nl][fo + 2] = kf.z; Kl[nl][fo + 3] = kf.w;
        Vl[nl][fo + 0] = vf.x; Vl[nl][fo + 1] = vf.y; Vl[nl][fo + 2] = vf.z; Vl[nl][fo + 3] = vf.w;
        vs4.x += vf.x; vs4.y += vf.y; vs4.z += vf.z; vs4.w += vf.w;
        __syncthreads();
        if (t < 32) {
            float s = 0.f;
#pragma unroll
            for (int d4 = 0; d4 < 8; d4++) {
                float4 kk = *reinterpret_cast<const float4*>(&Kl[t][d4 * 4]);
                s += kk.x * kk.x + kk.y * kk.y + kk.z * kk.z + kk.w * kk.w;
            }
            dgl[t] = 0.5f * s;
        }
        float uv[32];
        float cmax = -1e30f;
#pragma unroll
        for (int n = 0; n < 32; n++) {
            float u = 0.f;
#pragma unroll
            for (int d4 = 0; d4 < 8; d4++) {
                float4 kk = *reinterpret_cast<const float4*>(&Kl[n][d4 * 4]);
                u += pr[d4].x * kk.x + pr[d4].y * kk.y + pr[d4].z * kk.z + pr[d4].w * kk.w;
            }
            uv[n] = u;
            cmax = fmaxf(cmax, u);
        }
#pragma unroll
        for (int o = 32; o >= 1; o >>= 1) cmax = fmaxf(cmax, __shfl_xor(cmax, o));
        if (l == 0) red[w] = cmax;
        __syncthreads();
        float bm = fmaxf(fmaxf(red[0], red[1]), fmaxf(red[2], red[3]));
        if (bm > Lm) {
            float sc = __expf(Lm - bm);
#pragma unroll
            for (int d4 = 0; d4 < 8; d4++) {
                av[d4].x *= sc; av[d4].y *= sc; av[d4].z *= sc; av[d4].w *= sc;
            }
            asum *= sc;
            Lm = bm;
        }
#pragma unroll
        for (int n = 0; n < 32; n++) {
            float kp = __expf(uv[n] - dgl[n] - Lm);
            asum += kp;
#pragma unroll
            for (int d4 = 0; d4 < 8; d4++) {
                float4 vv = *reinterpret_cast<const float4*>(&Vl[n][d4 * 4]);
                av[d4].x += kp * vv.x; av[d4].y += kp * vv.y;
                av[d4].z += kp * vv.z; av[d4].w += kp * vv.w;
            }
        }
    }
    size_t base = ((size_t)bh * KV_P + blockIdx.y) * PSZ;
#pragma unroll
    for (int d4 = 0; d4 < 8; d4++)
        *reinterpret_cast<float4*>(&kvp[base + t * DH + d4 * 4]) = av[d4];
    kvp[base + 8192 + t] = asum;
    vred[t][0] = vs4.x; vred[t][1] = vs4.y; vred[t][2] = vs4.z; vred[t][3] = vs4.w;
    __syncthreads();
    if (t < 32) {
        int f4g = t >> 2, c = t & 3;
        float s = 0.f;
#pragma unroll
        for (int g = 0; g < 32; g++) s += vred[g * 8 + f4g][c];
        kvp[base + 8448 + t] = s;
    }
    if (t == 0) kvp[base + 8480] = Lm;
}

// ---------------- combine partials -> kvf, ksumf ----------------
__global__ __launch_bounds__(256) void kv_combine_kernel(const float* __restrict__ kvp,
                                                         float* __restrict__ kvf,
                                                         float* __restrict__ ksumf) {
    __shared__ float vst[32];
    int t = threadIdx.x;
    int bh = blockIdx.x;
    size_t base0 = (size_t)bh * KV_P * PSZ;
    float Lp[KV_P];
    float gm = -1e30f;
#pragma unroll
    for (int p = 0; p < KV_P; p++) {
        Lp[p] = kvp[base0 + p * PSZ + 8480];
        gm = fmaxf(gm, Lp[p]);
    }
    if (t < 32) {
        float s = 0.f;
#pragma unroll
        for (int p = 0; p < KV_P; p++) s += kvp[base0 + p * PSZ + 8448 + t];
        vst[t] = s;
    }
    __syncthreads();
    float4 av[8];
#pragma unroll
    for (int d4 = 0; d4 < 8; d4++) av[d4] = (float4){0.f, 0.f, 0.f, 0.f};
    float S = 0.f;
#pragma unroll
    for (int p = 0; p < KV_P; p++) {
        float e = __expf(Lp[p] - gm);
        size_t pb = base0 + p * PSZ;
#pragma unroll
        for (int d4 = 0; d4 < 8; d4++) {
            float4 a = *reinterpret_cast<const float4*>(&kvp[pb + t * DH + d4 * 4]);
            av[d4].x += e * a.x; av[d4].y += e * a.y; av[d4].z += e * a.z; av[d4].w += e * a.w;
        }
        S += e * kvp[pb + 8192 + t];
    }
#pragma unroll
    for (int d4 = 0; d4 < 8; d4++) {
        float4 o;
        o.x = (av[d4].x + 1e-4f * vst[d4 * 4 + 0]) * 0.0625f;
        o.y = (av[d4].y + 1e-4f * vst[d4 * 4 + 1]) * 0.0625f;
        o.z = (av[d4].z + 1e-4f * vst[d4 * 4 + 2]) * 0.0625f;
        o.w = (av[d4].w + 1e-4f * vst[d4 * 4 + 3]) * 0.0625f;
        *reinterpret_cast<float4*>(&kvf[(size_t)bh * M * DH + t * DH + d4 * 4]) = o;
    }
    ksumf[bh * M + t] = (S + 1e-4f * (float)N) * 0.0625f;
}

// ---------------- q-side fused attention ----------------
__global__ __launch_bounds__(256) void attn_kernel(const float* __restrict__ qkv,
                                                   const float* __restrict__ proj,
                                                   const float* __restrict__ kvf,
                                                   const float* __restrict__ ksumf,
                                                   unsigned short* __restrict__ attn16) {
    __shared__ float projL[256][36];
    __shared__ float qtL[32][36];
    __shared__ unsigned short qp[32][264];
    __shared__ float ksumL[256];
    __shared__ float zrow[32];
    int t = threadIdx.x;
    int bh = blockIdx.x, b = bh >> 3, h = bh & 7;
    int n0 = blockIdx.y * 32;

    // stage proj (own row), ksum, q-tile
#pragma unroll
    for (int d4 = 0; d4 < 8; d4++) {
        float4 p = *reinterpret_cast<const float4*>(&proj[t * DH + d4 * 4]);
        projL[t][d4 * 4 + 0] = p.x; projL[t][d4 * 4 + 1] = p.y;
        projL[t][d4 * 4 + 2] = p.z; projL[t][d4 * 4 + 3] = p.w;
    }
    ksumL[t] = ksumf[bh * M + t];
    {
        int r = t >> 3, fo = (t & 7) * 4;
        float4 q = *reinterpret_cast<const float4*>(
            &qkv[((size_t)(b * N + n0 + r)) * (3 * D) + h * DH + fo]);
        qtL[r][fo + 0] = q.x * NRM; qtL[r][fo + 1] = q.y * NRM;
        qtL[r][fo + 2] = q.z * NRM; qtL[r][fo + 3] = q.w * NRM;
    }
    __syncthreads();

    int r = t >> 3, mg = t & 7;
    float4 qreg[8];
    float dg = 0.f;
#pragma unroll
    for (int d4 = 0; d4 < 8; d4++) {
        qreg[d4] = *reinterpret_cast<const float4*>(&qtL[r][d4 * 4]);
        dg += qreg[d4].x * qreg[d4].x + qreg[d4].y * qreg[d4].y +
              qreg[d4].z * qreg[d4].z + qreg[d4].w * qreg[d4].w;
    }
    dg *= 0.5f;

    float uv[32];
    float umax = -1e30f;
#pragma unroll
    for (int j = 0; j < 32; j++) {
        int m = mg + j * 8;
        float u = 0.f;
#pragma unroll
        for (int d4 = 0; d4 < 8; d4++) {
            float4 p = *reinterpret_cast<const float4*>(&projL[m][d4 * 4]);
            u += qreg[d4].x * p.x + qreg[d4].y * p.y + qreg[d4].z * p.z + qreg[d4].w * p.w;
        }
        uv[j] = u;
        umax = fmaxf(umax, u);
    }
    umax = fmaxf(umax, __shfl_xor(umax, 1));
    umax = fmaxf(umax, __shfl_xor(umax, 2));
    umax = fmaxf(umax, __shfl_xor(umax, 4));
    float zs = 0.f;
#pragma unroll
    for (int j = 0; j < 32; j++) {
        int m = mg + j * 8;
        float p = (__expf(uv[j] - dg - umax) + 1e-4f) * 0.0625f;
        qp[r][m] = f2bf(p);
        zs += p * ksumL[m];
    }
    zs += __shfl_xor(zs, 1);
    zs += __shfl_xor(zs, 2);
    zs += __shfl_xor(zs, 4);
    if (mg == 0) zrow[r] = 1.0f / (zs + 1e-6f);
    __syncthreads();

    int r2 = t >> 3, dd0 = (t & 7) * 4;
    const float* kvp_ = kvf + (size_t)bh * M * DH + dd0;
    float o0 = 0.f, o1 = 0.f, o2 = 0.f, o3 = 0.f;
#pragma unroll 8
    for (int m = 0; m < M; m++) {
        float p = bf2f(qp[r2][m]);
        float4 kr = *reinterpret_cast<const float4*>(&kvp_[m * DH]);
        o0 += p * kr.x; o1 += p * kr.y; o2 += p * kr.z; o3 += p * kr.w;
    }
    float z = zrow[r2];
    ushort4 o;
    o.x = f2bf(o0 * z); o.y = f2bf(o1 * z); o.z = f2bf(o2 * z); o.w = f2bf(o3 * z);
    *reinterpret_cast<ushort4*>(
        &attn16[((size_t)(b * N + n0 + r2)) * D + h * DH + dd0]) = o;
}

extern "C" void kernel_launch(void* const* d_in, const int* in_sizes, int n_in,
                              void* d_out, int out_size, void* d_ws, size_t ws_size,
                              hipStream_t stream) {
    const float* x = (const float*)d_in[0];
    const float* pos = (const float*)d_in[1];
    const float* g1 = (const float*)d_in[2];
    const float* b1 = (const float*)d_in[3];
    const float* g2 = (const float*)d_in[4];
    const float* b2 = (const float*)d_in[5];
    const float* Wqkv = (const float*)d_in[6];
    const float* Wproj = (const float*)d_in[7];
    const float* bproj = (const float*)d_in[8];
    const float* W1 = (const float*)d_in[9];
    const float* b1m = (const float*)d_in[10];
    const float* W2 = (const float*)d_in[11];
    const float* b2m = (const float*)d_in[12];
    const float* projm = (const float*)d_in[13];

    float* h = (float*)d_out;
    float* f = (float*)d_ws;
    unsigned short* wbf = (unsigned short*)f;      f += 1572864;   // 3.14M bf16 weights
    unsigned short* ln16 = (unsigned short*)f;     f += 4194304;   // B*N*D bf16
    float* qkv = f;                                f += 25165824;  // B*N*3D fp32
    unsigned short* hid16 = (unsigned short*)qkv;                  // aliases qkv (dead by MLP)
    unsigned short* attn16 = (unsigned short*)f;   f += 4194304;   // B*N*D bf16
    float* kvp = f;                                f += (size_t)64 * KV_P * PSZ;
    float* kvf = f;                                f += 524288;    // 64*256*32
    float* ksumf = f;                              f += 16384;     // 64*256

    // ---- weight prep: bf16 transpose ----
    for (int l = 0; l < DEPTH; l++) {
        size_t lb = (size_t)l * 786432;
        wtrans_kernel<<<dim3(768 / 32, 256 / 32), 256, 0, stream>>>(
            Wqkv + (size_t)l * D * 3 * D, wbf + lb + 0, 256, 768);
        wtrans_kernel<<<dim3(256 / 32, 256 / 32), 256, 0, stream>>>(
            Wproj + (size_t)l * D * D, wbf + lb + 196608, 256, 256);
        wtrans_kernel<<<dim3(1024 / 32, 256 / 32), 256, 0, stream>>>(
            W1 + (size_t)l * D * HID, wbf + lb + 262144, 256, 1024);
        wtrans_kernel<<<dim3(256 / 32, 1024 / 32), 256, 0, stream>>>(
            W2 + (size_t)l * HID * D, wbf + lb + 524288, 1024, 256);
    }

    add_pos_kernel<<<B * N * D / 256, 256, 0, stream>>>(x, pos, h);

    for (int l = 0; l < DEPTH; l++) {
        size_t lb = (size_t)l * 786432;
        const unsigned short* wqT = wbf + lb + 0;
        const unsigned short* wpT = wbf + lb + 196608;
        const unsigned short* w1T = wbf + lb + 262144;
        const unsigned short* w2T = wbf + lb + 524288;
        const float* bp = bproj + (size_t)l * D;
        const float* b1l = b1m + (size_t)l * HID;
        const float* b2l = b2m + (size_t)l * D;
        const float* prl = projm + (size_t)l * M * DH;

        ln_kernel<<<B * N / 4, 256, 0, stream>>>(h, g1, b1, ln16);
        mgemm_kernel<false, false, false, false><<<dim3(768 / 128, B * N / 128), 256, 0, stream>>>(
            ln16, wqT, nullptr, qkv, nullptr, 256, 768);
        kv_kernel<<<dim3(B * H, KV_P), 256, 0, stream>>>(qkv, prl, kvp);
        kv_combine_kernel<<<B * H, 256, 0, stream>>>(kvp, kvf, ksumf);
        attn_kernel<<<dim3(B * H, N / 32), 256, 0, stream>>>(qkv, prl, kvf, ksumf, attn16);
        mgemm_kernel<true, false, true, false><<<dim3(256 / 128, B * N / 128), 256, 0, stream>>>(
            attn16, wpT, bp, h, nullptr, 256, 256);
        ln_kernel<<<B * N / 4, 256, 0, stream>>>(h, g2, b2, ln16);
        mgemm_kernel<true, true, false, true><<<dim3(1024 / 128, B * N / 128), 256, 0, stream>>>(
            ln16, w1T, b1l, nullptr, hid16, 256, 1024);
        mgemm_kernel<true, false, true, false><<<dim3(256 / 128, B * N / 128), 256, 0, stream>>>(
            hid16, w2T, b2l, h, nullptr, 1024, 256);
    }
}

// Round 4
// 1227.263 us; speedup vs baseline: 9.7760x; 2.2343x over previous
//
#include <hip/hip_runtime.h>
#include <hip/hip_bf16.h>
#include <math.h>

#define B 8
#define N 4096
#define D 256
#define H 8
#define DH 32
#define M 256
#define DEPTH 4
#define HID 1024
#define NRM 0.4204482076268573f   // 32^-0.25

typedef __attribute__((ext_vector_type(8))) short short8;
typedef __attribute__((ext_vector_type(4))) float f32x4;

static __device__ __forceinline__ unsigned short f2bf(float f) {
    __hip_bfloat16 h = __float2bfloat16(f);
    return __builtin_bit_cast(unsigned short, h);
}

// ---------------- h = x + pos ----------------
__global__ void add_pos_kernel(const float* __restrict__ x, const float* __restrict__ pos,
                               float* __restrict__ h) {
    int i = blockIdx.x * 256 + threadIdx.x;
    int nd = i % (N * D);
    h[i] = x[i] + pos[nd];
}

// ---------------- proj fp32 -> bf16 copy ----------------
__global__ void projbf_kernel(const float* __restrict__ in, unsigned short* __restrict__ out) {
    int i = blockIdx.x * 256 + threadIdx.x;     // DEPTH*M*DH elements
    out[i] = f2bf(in[i]);
}

// ---------------- weight fp32 (K x N) -> bf16 transposed (N x K) ----------------
__global__ __launch_bounds__(256) void wtrans_kernel(const float* __restrict__ in,
                                                     unsigned short* __restrict__ out,
                                                     int Kd, int Nd) {
    __shared__ float tl[32][33];
    int n0 = blockIdx.x * 32, k0 = blockIdx.y * 32;
    int t = threadIdx.x;
    int kk = t >> 3, c4 = (t & 7) * 4;
    float4 v = *reinterpret_cast<const float4*>(&in[(size_t)(k0 + kk) * Nd + n0 + c4]);
    tl[kk][c4 + 0] = v.x; tl[kk][c4 + 1] = v.y; tl[kk][c4 + 2] = v.z; tl[kk][c4 + 3] = v.w;
    __syncthreads();
    int nn = t >> 3, k4 = (t & 7) * 4;
    ushort4 o;
    o.x = f2bf(tl[k4 + 0][nn]); o.y = f2bf(tl[k4 + 1][nn]);
    o.z = f2bf(tl[k4 + 2][nn]); o.w = f2bf(tl[k4 + 3][nn]);
    *reinterpret_cast<ushort4*>(&out[(size_t)(n0 + nn) * Kd + k0 + k4]) = o;
}

// ---------------- LayerNorm -> bf16 ----------------
__global__ __launch_bounds__(256) void ln_kernel(const float* __restrict__ in,
                                                 const float* __restrict__ g,
                                                 const float* __restrict__ bb,
                                                 unsigned short* __restrict__ out) {
    int wave = threadIdx.x >> 6, lane = threadIdx.x & 63;
    long row = (long)blockIdx.x * 4 + wave;
    float4 v = reinterpret_cast<const float4*>(in + row * D)[lane];
    float s = v.x + v.y + v.z + v.w;
#pragma unroll
    for (int o = 32; o >= 1; o >>= 1) s += __shfl_xor(s, o);
    float mu = s * (1.0f / D);
    float d0 = v.x - mu, d1 = v.y - mu, d2 = v.z - mu, d3 = v.w - mu;
    float ss = d0 * d0 + d1 * d1 + d2 * d2 + d3 * d3;
#pragma unroll
    for (int o = 32; o >= 1; o >>= 1) ss += __shfl_xor(ss, o);
    float inv = rsqrtf(ss * (1.0f / D) + 1e-6f);
    float4 gv = reinterpret_cast<const float4*>(g)[lane];
    float4 bv = reinterpret_cast<const float4*>(bb)[lane];
    ushort4 o4;
    o4.x = f2bf(d0 * inv * gv.x + bv.x);
    o4.y = f2bf(d1 * inv * gv.y + bv.y);
    o4.z = f2bf(d2 * inv * gv.z + bv.z);
    o4.w = f2bf(d3 * inv * gv.w + bv.w);
    *reinterpret_cast<ushort4*>(&out[row * D + lane * 4]) = o4;
}

// ---------------- bf16 MFMA GEMM: C = A(MxK) @ Bt(NxK)^T ----------------
template <bool BIAS, bool GELU_ACT, bool RESID, bool OUT16>
__global__ __launch_bounds__(256) void mgemm_kernel(const unsigned short* __restrict__ A,
                                                    const unsigned short* __restrict__ Bt,
                                                    const float* __restrict__ bias,
                                                    float* __restrict__ C,
                                                    unsigned short* __restrict__ O16,
                                                    int K, int Nc) {
    __shared__ short Als[128][32];
    __shared__ short Bls[128][32];
    int t = threadIdx.x;
    int l = t & 63, w = t >> 6;
    int wr = w >> 1, wc = w & 1;
    long m0 = (long)blockIdx.y * 128;
    int n0 = blockIdx.x * 128;
    int lr = l & 15;
    int kp8 = (l >> 4) * 8;
    int srow = t >> 2, skoff = (t & 3) * 8;

    f32x4 acc[4][4];
#pragma unroll
    for (int i = 0; i < 4; i++)
#pragma unroll
        for (int j = 0; j < 4; j++) acc[i][j] = (f32x4){0.f, 0.f, 0.f, 0.f};

    for (int k0 = 0; k0 < K; k0 += 32) {
#pragma unroll
        for (int it = 0; it < 2; it++) {
            int r = srow + it * 64;
            short8 va = *reinterpret_cast<const short8*>(&A[(size_t)(m0 + r) * K + k0 + skoff]);
            *reinterpret_cast<short8*>(&Als[r][skoff]) = va;
            short8 vb = *reinterpret_cast<const short8*>(&Bt[(size_t)(n0 + r) * K + k0 + skoff]);
            *reinterpret_cast<short8*>(&Bls[r][skoff]) = vb;
        }
        __syncthreads();
        short8 a[4], b[4];
#pragma unroll
        for (int i = 0; i < 4; i++)
            a[i] = *reinterpret_cast<const short8*>(&Als[wr * 64 + i * 16 + lr][kp8]);
#pragma unroll
        for (int j = 0; j < 4; j++)
            b[j] = *reinterpret_cast<const short8*>(&Bls[wc * 64 + j * 16 + lr][kp8]);
#pragma unroll
        for (int i = 0; i < 4; i++)
#pragma unroll
            for (int j = 0; j < 4; j++)
                acc[i][j] = __builtin_amdgcn_mfma_f32_16x16x32_bf16(a[i], b[j], acc[i][j], 0, 0, 0);
        __syncthreads();
    }

    int rif = (l >> 4) * 4;
#pragma unroll
    for (int i = 0; i < 4; i++) {
#pragma unroll
        for (int j = 0; j < 4; j++) {
            int gcol = n0 + wc * 64 + j * 16 + lr;
            float bv = BIAS ? bias[gcol] : 0.f;
#pragma unroll
            for (int r = 0; r < 4; r++) {
                long grow = m0 + wr * 64 + i * 16 + rif + r;
                float v = acc[i][j][r] + bv;
                if (GELU_ACT) v = 0.5f * v * (1.0f + erff(v * 0.70710678118654752f));
                if (OUT16) {
                    O16[grow * Nc + gcol] = f2bf(v);
                } else if (RESID) {
                    C[grow * Nc + gcol] += v;
                } else {
                    C[grow * Nc + gcol] = v;
                }
            }
        }
    }
}

// ---------------- kv: MFMA u + online-max + MFMA kp^T @ v, partials ----------------
#define KV_P 8
#define KV_ROWS (N / KV_P)      // 512
#define PSZ 8484                // 8192 acc + 256 asum + 32 vsum + 1 Lm + pad
__global__ __launch_bounds__(256) void kv_kernel(const float* __restrict__ qkv,
                                                 const unsigned short* __restrict__ projbf,
                                                 float* __restrict__ kvp) {
    __shared__ __align__(16) unsigned short kp_sT[256][72];   // [m][n-chunk]
    __shared__ __align__(16) unsigned short vT_s[32][72];     // [d][n-chunk]
    __shared__ float red[4];
    __shared__ float asumred[4][256];
    __shared__ float vred[256][4];
    int t = threadIdx.x;
    int l = t & 63, w = t >> 6;
    int lr = l & 15, lg = l >> 4;
    int bh = blockIdx.x, b = bh >> 3, h = bh & 7;
    int n0 = blockIdx.y * KV_ROWS;

    f32x4 kvacc[4][2];
#pragma unroll
    for (int mf = 0; mf < 4; mf++)
#pragma unroll
        for (int dd = 0; dd < 2; dd++) kvacc[mf][dd] = (f32x4){0.f, 0.f, 0.f, 0.f};
    float asum_p[16];
#pragma unroll
    for (int f = 0; f < 16; f++) asum_p[f] = 0.f;
    float4 vs4 = {0.f, 0.f, 0.f, 0.f};
    float Lm = -1e30f;

    for (int c = 0; c < KV_ROWS / 64; c++) {
        // ---- K rows -> A-frag (+ dg) ----
        size_t kbase = ((size_t)(b * N) + n0 + c * 64 + w * 16 + lr) * 768 + 256 + h * 32 + lg * 8;
        float4 ka = *reinterpret_cast<const float4*>(qkv + kbase);
        float4 kb = *reinterpret_cast<const float4*>(qkv + kbase + 4);
        ka.x *= NRM; ka.y *= NRM; ka.z *= NRM; ka.w *= NRM;
        kb.x *= NRM; kb.y *= NRM; kb.z *= NRM; kb.w *= NRM;
        float sq = ka.x * ka.x + ka.y * ka.y + ka.z * ka.z + ka.w * ka.w +
                   kb.x * kb.x + kb.y * kb.y + kb.z * kb.z + kb.w * kb.w;
        sq += __shfl_xor(sq, 16);
        sq += __shfl_xor(sq, 32);
        short8 aq;
        aq[0] = (short)f2bf(ka.x); aq[1] = (short)f2bf(ka.y);
        aq[2] = (short)f2bf(ka.z); aq[3] = (short)f2bf(ka.w);
        aq[4] = (short)f2bf(kb.x); aq[5] = (short)f2bf(kb.y);
        aq[6] = (short)f2bf(kb.z); aq[7] = (short)f2bf(kb.w);
        // ---- u = k @ projT via mfma ----
        f32x4 ua[16];
#pragma unroll
        for (int f = 0; f < 16; f++) {
            short8 bq = *reinterpret_cast<const short8*>(projbf + (f * 16 + lr) * 32 + lg * 8);
            ua[f] = __builtin_amdgcn_mfma_f32_16x16x32_bf16(aq, bq, (f32x4){0.f, 0.f, 0.f, 0.f}, 0, 0, 0);
        }
        // ---- chunk max (block-wide) ----
        float cm = -1e30f;
#pragma unroll
        for (int f = 0; f < 16; f++)
#pragma unroll
            for (int r = 0; r < 4; r++) cm = fmaxf(cm, ua[f][r]);
#pragma unroll
        for (int o = 1; o < 64; o <<= 1) cm = fmaxf(cm, __shfl_xor(cm, o));
        if (l == 0) red[w] = cm;
        __syncthreads();
        float bm = fmaxf(fmaxf(red[0], red[1]), fmaxf(red[2], red[3]));
        if (bm > Lm) {
            float sc = __expf(Lm - bm);
#pragma unroll
            for (int mf = 0; mf < 4; mf++)
#pragma unroll
                for (int dd = 0; dd < 2; dd++) {
                    kvacc[mf][dd][0] *= sc; kvacc[mf][dd][1] *= sc;
                    kvacc[mf][dd][2] *= sc; kvacc[mf][dd][3] *= sc;
                }
#pragma unroll
            for (int f = 0; f < 16; f++) asum_p[f] *= sc;
            Lm = bm;
        }
        float dgr[4];
#pragma unroll
        for (int r = 0; r < 4; r++) dgr[r] = 0.5f * __shfl(sq, lg * 4 + r);
        // ---- kp = exp(u - dg - Lm) -> LDS transposed ----
#pragma unroll
        for (int f = 0; f < 16; f++) {
#pragma unroll
            for (int r = 0; r < 4; r++) {
                float p = __expf(ua[f][r] - dgr[r] - Lm);
                asum_p[f] += p;
                kp_sT[f * 16 + lr][w * 16 + lg * 4 + r] = f2bf(p);
            }
        }
        // ---- stage v^T (bf16) ----
#pragma unroll
        for (int ii = 0; ii < 2; ii++) {
            int idx = t + ii * 256;
            int nn = idx >> 3, dz = (idx & 7) * 4;
            const float* vp = qkv + ((size_t)(b * N) + n0 + c * 64 + nn) * 768 + 512 + h * 32 + dz;
            float4 vv = *reinterpret_cast<const float4*>(vp);
            vs4.x += vv.x; vs4.y += vv.y; vs4.z += vv.z; vs4.w += vv.w;
            vT_s[dz + 0][nn] = f2bf(vv.x); vT_s[dz + 1][nn] = f2bf(vv.y);
            vT_s[dz + 2][nn] = f2bf(vv.z); vT_s[dz + 3][nn] = f2bf(vv.w);
        }
        __syncthreads();
        // ---- kv += kp^T @ v ----
#pragma unroll
        for (int ks = 0; ks < 2; ks++) {
            short8 bv0 = *reinterpret_cast<const short8*>(&vT_s[lr][ks * 32 + lg * 8]);
            short8 bv1 = *reinterpret_cast<const short8*>(&vT_s[16 + lr][ks * 32 + lg * 8]);
#pragma unroll
            for (int mf = 0; mf < 4; mf++) {
                short8 am = *reinterpret_cast<const short8*>(&kp_sT[w * 64 + mf * 16 + lr][ks * 32 + lg * 8]);
                kvacc[mf][0] = __builtin_amdgcn_mfma_f32_16x16x32_bf16(am, bv0, kvacc[mf][0], 0, 0, 0);
                kvacc[mf][1] = __builtin_amdgcn_mfma_f32_16x16x32_bf16(am, bv1, kvacc[mf][1], 0, 0, 0);
            }
        }
    }
    // ---- asum wave reduce + stores ----
#pragma unroll
    for (int f = 0; f < 16; f++) {
        asum_p[f] += __shfl_xor(asum_p[f], 16);
        asum_p[f] += __shfl_xor(asum_p[f], 32);
    }
    if (l < 16) {
#pragma unroll
        for (int f = 0; f < 16; f++) asumred[w][f * 16 + l] = asum_p[f];
    }
    vred[t][0] = vs4.x; vred[t][1] = vs4.y; vred[t][2] = vs4.z; vred[t][3] = vs4.w;
    __syncthreads();
    size_t base = ((size_t)bh * KV_P + blockIdx.y) * PSZ;
#pragma unroll
    for (int mf = 0; mf < 4; mf++)
#pragma unroll
        for (int dd = 0; dd < 2; dd++)
#pragma unroll
            for (int r = 0; r < 4; r++) {
                int m = w * 64 + mf * 16 + lg * 4 + r;
                int d = dd * 16 + lr;
                kvp[base + m * 32 + d] = kvacc[mf][dd][r];
            }
    {
        float s = asumred[0][t] + asumred[1][t] + asumred[2][t] + asumred[3][t];
        kvp[base + 8192 + t] = s;
    }
    if (t < 32) {
        int f4g = t >> 2, cc = t & 3;
        float s = 0.f;
#pragma unroll
        for (int g = 0; g < 32; g++) s += vred[g * 8 + f4g][cc];
        kvp[base + 8448 + t] = s;
    }
    if (t == 0) kvp[base + 8480] = Lm;
}

// ---------------- combine partials -> kvT bf16, ksum ----------------
__global__ __launch_bounds__(256) void kv_combine_kernel(const float* __restrict__ kvp,
                                                         unsigned short* __restrict__ kvTb,
                                                         float* __restrict__ ksumf) {
    __shared__ float vst[32];
    int t = threadIdx.x;
    int bh = blockIdx.x;
    size_t base0 = (size_t)bh * KV_P * PSZ;
    float Lp[KV_P];
    float gm = -1e30f;
#pragma unroll
    for (int p = 0; p < KV_P; p++) {
        Lp[p] = kvp[base0 + p * PSZ + 8480];
        gm = fmaxf(gm, Lp[p]);
    }
    if (t < 32) {
        float s = 0.f;
#pragma unroll
        for (int p = 0; p < KV_P; p++) s += kvp[base0 + p * PSZ + 8448 + t];
        vst[t] = s;
    }
    __syncthreads();
    float4 av[8];
#pragma unroll
    for (int d4 = 0; d4 < 8; d4++) av[d4] = (float4){0.f, 0.f, 0.f, 0.f};
    float S = 0.f;
#pragma unroll
    for (int p = 0; p < KV_P; p++) {
        float e = __expf(Lp[p] - gm);
        size_t pb = base0 + p * PSZ;
#pragma unroll
        for (int d4 = 0; d4 < 8; d4++) {
            float4 a = *reinterpret_cast<const float4*>(&kvp[pb + t * 32 + d4 * 4]);
            av[d4].x += e * a.x; av[d4].y += e * a.y; av[d4].z += e * a.z; av[d4].w += e * a.w;
        }
        S += e * kvp[pb + 8192 + t];
    }
#pragma unroll
    for (int d4 = 0; d4 < 8; d4++) {
        float o0 = (av[d4].x + 1e-4f * vst[d4 * 4 + 0]) * 0.0625f;
        float o1 = (av[d4].y + 1e-4f * vst[d4 * 4 + 1]) * 0.0625f;
        float o2 = (av[d4].z + 1e-4f * vst[d4 * 4 + 2]) * 0.0625f;
        float o3 = (av[d4].w + 1e-4f * vst[d4 * 4 + 3]) * 0.0625f;
        kvTb[((size_t)bh * 32 + d4 * 4 + 0) * 256 + t] = f2bf(o0);
        kvTb[((size_t)bh * 32 + d4 * 4 + 1) * 256 + t] = f2bf(o1);
        kvTb[((size_t)bh * 32 + d4 * 4 + 2) * 256 + t] = f2bf(o2);
        kvTb[((size_t)bh * 32 + d4 * 4 + 3) * 256 + t] = f2bf(o3);
    }
    ksumf[bh * 256 + t] = (S + 1e-4f * (float)N) * 0.0625f;
}

// ---------------- q-side fused attention (MFMA) ----------------
__global__ __launch_bounds__(256) void attn_kernel(const float* __restrict__ qkv,
                                                   const unsigned short* __restrict__ projbf,
                                                   const unsigned short* __restrict__ kvTb,
                                                   const float* __restrict__ ksumf,
                                                   unsigned short* __restrict__ attn16) {
    __shared__ __align__(16) unsigned short qp_s[64][264];
    int t = threadIdx.x;
    int l = t & 63, w = t >> 6;
    int lr = l & 15, lg = l >> 4;
    int bh = blockIdx.x, b = bh >> 3, h = bh & 7;
    int n0 = blockIdx.y * 64;

    float ksr[16];
#pragma unroll
    for (int f = 0; f < 16; f++) ksr[f] = ksumf[bh * 256 + f * 16 + lr];

    // ---- q A-frag + dg ----
    size_t qbase = ((size_t)(b * N) + n0 + w * 16 + lr) * 768 + h * 32 + lg * 8;
    float4 qa = *reinterpret_cast<const float4*>(qkv + qbase);
    float4 qb = *reinterpret_cast<const float4*>(qkv + qbase + 4);
    qa.x *= NRM; qa.y *= NRM; qa.z *= NRM; qa.w *= NRM;
    qb.x *= NRM; qb.y *= NRM; qb.z *= NRM; qb.w *= NRM;
    float sq = qa.x * qa.x + qa.y * qa.y + qa.z * qa.z + qa.w * qa.w +
               qb.x * qb.x + qb.y * qb.y + qb.z * qb.z + qb.w * qb.w;
    sq += __shfl_xor(sq, 16);
    sq += __shfl_xor(sq, 32);
    short8 aq;
    aq[0] = (short)f2bf(qa.x); aq[1] = (short)f2bf(qa.y);
    aq[2] = (short)f2bf(qa.z); aq[3] = (short)f2bf(qa.w);
    aq[4] = (short)f2bf(qb.x); aq[5] = (short)f2bf(qb.y);
    aq[6] = (short)f2bf(qb.z); aq[7] = (short)f2bf(qb.w);

    // ---- u = q @ projT ----
    f32x4 ua[16];
#pragma unroll
    for (int f = 0; f < 16; f++) {
        short8 bq = *reinterpret_cast<const short8*>(projbf + (f * 16 + lr) * 32 + lg * 8);
        ua[f] = __builtin_amdgcn_mfma_f32_16x16x32_bf16(aq, bq, (f32x4){0.f, 0.f, 0.f, 0.f}, 0, 0, 0);
    }

    // ---- rowmax, dg, qp, z ----
    float mx[4], dgr[4], zs[4];
#pragma unroll
    for (int r = 0; r < 4; r++) {
        float m_ = -1e30f;
#pragma unroll
        for (int f = 0; f < 16; f++) m_ = fmaxf(m_, ua[f][r]);
#pragma unroll
        for (int o = 1; o < 16; o <<= 1) m_ = fmaxf(m_, __shfl_xor(m_, o));
        mx[r] = m_;
        dgr[r] = 0.5f * __shfl(sq, lg * 4 + r);
        zs[r] = 0.f;
    }
#pragma unroll
    for (int f = 0; f < 16; f++) {
#pragma unroll
        for (int r = 0; r < 4; r++) {
            float p = (__expf(ua[f][r] - dgr[r] - mx[r]) + 1e-4f) * 0.0625f;
            zs[r] += p * ksr[f];
            qp_s[w * 16 + lg * 4 + r][f * 16 + lr] = f2bf(p);
        }
    }
    float zf[4];
#pragma unroll
    for (int r = 0; r < 4; r++) {
#pragma unroll
        for (int o = 1; o < 16; o <<= 1) zs[r] += __shfl_xor(zs[r], o);
        zf[r] = 1.0f / (zs[r] + 1e-6f);
    }
    __syncthreads();

    // ---- out = qp @ kv ----
    f32x4 oacc[2];
    oacc[0] = (f32x4){0.f, 0.f, 0.f, 0.f};
    oacc[1] = (f32x4){0.f, 0.f, 0.f, 0.f};
    const unsigned short* kvb = kvTb + (size_t)bh * 32 * 256;
#pragma unroll
    for (int k0 = 0; k0 < 8; k0++) {
        short8 am = *reinterpret_cast<const short8*>(&qp_s[w * 16 + lr][k0 * 32 + lg * 8]);
        short8 b0 = *reinterpret_cast<const short8*>(kvb + (size_t)lr * 256 + k0 * 32 + lg * 8);
        short8 b1 = *reinterpret_cast<const short8*>(kvb + (size_t)(16 + lr) * 256 + k0 * 32 + lg * 8);
        oacc[0] = __builtin_amdgcn_mfma_f32_16x16x32_bf16(am, b0, oacc[0], 0, 0, 0);
        oacc[1] = __builtin_amdgcn_mfma_f32_16x16x32_bf16(am, b1, oacc[1], 0, 0, 0);
    }
#pragma unroll
    for (int dd = 0; dd < 2; dd++)
#pragma unroll
        for (int r = 0; r < 4; r++) {
            size_t row = (size_t)(b * N) + n0 + w * 16 + lg * 4 + r;
            int col = h * 32 + dd * 16 + lr;
            attn16[row * 256 + col] = f2bf(oacc[dd][r] * zf[r]);
        }
}

extern "C" void kernel_launch(void* const* d_in, const int* in_sizes, int n_in,
                              void* d_out, int out_size, void* d_ws, size_t ws_size,
                              hipStream_t stream) {
    const float* x = (const float*)d_in[0];
    const float* pos = (const float*)d_in[1];
    const float* g1 = (const float*)d_in[2];
    const float* b1 = (const float*)d_in[3];
    const float* g2 = (const float*)d_in[4];
    const float* b2 = (const float*)d_in[5];
    const float* Wqkv = (const float*)d_in[6];
    const float* Wproj = (const float*)d_in[7];
    const float* bproj = (const float*)d_in[8];
    const float* W1 = (const float*)d_in[9];
    const float* b1m = (const float*)d_in[10];
    const float* W2 = (const float*)d_in[11];
    const float* b2m = (const float*)d_in[12];
    const float* projm = (const float*)d_in[13];

    float* h = (float*)d_out;
    float* f = (float*)d_ws;
    unsigned short* wbf = (unsigned short*)f;      f += 1572864;   // 4 layers x 786432 bf16 shorts
    unsigned short* projb = (unsigned short*)f;    f += 16384;     // DEPTH*256*32 bf16
    unsigned short* ln16 = (unsigned short*)f;     f += 4194304;   // B*N*D bf16
    float* qkv = f;                                f += 25165824;  // B*N*3D fp32
    unsigned short* hid16 = (unsigned short*)qkv;                  // aliases qkv (dead by MLP)
    unsigned short* attn16 = (unsigned short*)f;   f += 4194304;   // B*N*D bf16
    float* kvp = f;                                f += (size_t)64 * KV_P * PSZ;
    unsigned short* kvTb = (unsigned short*)f;     f += 262144;    // 64*32*256 bf16
    float* ksumf = f;                              f += 16384;     // 64*256

    // ---- weight prep ----
    for (int l = 0; l < DEPTH; l++) {
        size_t lb = (size_t)l * 786432;
        wtrans_kernel<<<dim3(768 / 32, 256 / 32), 256, 0, stream>>>(
            Wqkv + (size_t)l * D * 3 * D, wbf + lb + 0, 256, 768);
        wtrans_kernel<<<dim3(256 / 32, 256 / 32), 256, 0, stream>>>(
            Wproj + (size_t)l * D * D, wbf + lb + 196608, 256, 256);
        wtrans_kernel<<<dim3(1024 / 32, 256 / 32), 256, 0, stream>>>(
            W1 + (size_t)l * D * HID, wbf + lb + 262144, 256, 1024);
        wtrans_kernel<<<dim3(256 / 32, 1024 / 32), 256, 0, stream>>>(
            W2 + (size_t)l * HID * D, wbf + lb + 524288, 1024, 256);
    }
    projbf_kernel<<<DEPTH * M * DH / 256, 256, 0, stream>>>(projm, projb);

    add_pos_kernel<<<B * N * D / 256, 256, 0, stream>>>(x, pos, h);

    for (int l = 0; l < DEPTH; l++) {
        size_t lb = (size_t)l * 786432;
        const unsigned short* wqT = wbf + lb + 0;
        const unsigned short* wpT = wbf + lb + 196608;
        const unsigned short* w1T = wbf + lb + 262144;
        const unsigned short* w2T = wbf + lb + 524288;
        const float* bp = bproj + (size_t)l * D;
        const float* b1l = b1m + (size_t)l * HID;
        const float* b2l = b2m + (size_t)l * D;
        const unsigned short* prb = projb + (size_t)l * M * DH;

        ln_kernel<<<B * N / 4, 256, 0, stream>>>(h, g1, b1, ln16);
        mgemm_kernel<false, false, false, false><<<dim3(768 / 128, B * N / 128), 256, 0, stream>>>(
            ln16, wqT, nullptr, qkv, nullptr, 256, 768);
        kv_kernel<<<dim3(B * H, KV_P), 256, 0, stream>>>(qkv, prb, kvp);
        kv_combine_kernel<<<B * H, 256, 0, stream>>>(kvp, kvTb, ksumf);
        attn_kernel<<<dim3(B * H, N / 64), 256, 0, stream>>>(qkv, prb, kvTb, ksumf, attn16);
        mgemm_kernel<true, false, true, false><<<dim3(256 / 128, B * N / 128), 256, 0, stream>>>(
            attn16, wpT, bp, h, nullptr, 256, 256);
        ln_kernel<<<B * N / 4, 256, 0, stream>>>(h, g2, b2, ln16);
        mgemm_kernel<true, true, false, true><<<dim3(1024 / 128, B * N / 128), 256, 0, stream>>>(
            ln16, w1T, b1l, nullptr, hid16, 256, 1024);
        mgemm_kernel<true, false, true, false><<<dim3(256 / 128, B * N / 128), 256, 0, stream>>>(
            hid16, w2T, b2l, h, nullptr, 1024, 256);
    }
}

// Round 5
// 1140.160 us; speedup vs baseline: 10.5229x; 1.0764x over previous
//
#include <hip/hip_runtime.h>
#include <hip/hip_bf16.h>
#include <math.h>

#define B 8
#define N 4096
#define D 256
#define H 8
#define DH 32
#define M 256
#define DEPTH 4
#define HID 1024
#define NRM 0.4204482076268573f   // 32^-0.25

typedef __attribute__((ext_vector_type(8))) short short8;
typedef __attribute__((ext_vector_type(4))) float f32x4;

static __device__ __forceinline__ unsigned short f2bf(float f) {
    __hip_bfloat16 h = __float2bfloat16(f);
    return __builtin_bit_cast(unsigned short, h);
}
static __device__ __forceinline__ float bfu2f(unsigned short u) {
    unsigned int x = ((unsigned int)u) << 16;
    return __builtin_bit_cast(float, x);
}

// ---------------- h = x + pos ----------------
__global__ void add_pos_kernel(const float* __restrict__ x, const float* __restrict__ pos,
                               float* __restrict__ h) {
    int i = blockIdx.x * 256 + threadIdx.x;
    int nd = i % (N * D);
    h[i] = x[i] + pos[nd];
}

// ---------------- proj fp32 -> bf16 copy ----------------
__global__ void projbf_kernel(const float* __restrict__ in, unsigned short* __restrict__ out) {
    int i = blockIdx.x * 256 + threadIdx.x;     // DEPTH*M*DH elements
    out[i] = f2bf(in[i]);
}

// ---- weight fp32 (K x N) -> bf16 transposed (N x K), cols < slim scaled by NRM ----
__global__ __launch_bounds__(256) void wtrans_kernel(const float* __restrict__ in,
                                                     unsigned short* __restrict__ out,
                                                     int Kd, int Nd, int slim) {
    __shared__ float tl[32][33];
    int n0 = blockIdx.x * 32, k0 = blockIdx.y * 32;
    int t = threadIdx.x;
    int kk = t >> 3, c4 = (t & 7) * 4;
    float4 v = *reinterpret_cast<const float4*>(&in[(size_t)(k0 + kk) * Nd + n0 + c4]);
    tl[kk][c4 + 0] = v.x; tl[kk][c4 + 1] = v.y; tl[kk][c4 + 2] = v.z; tl[kk][c4 + 3] = v.w;
    __syncthreads();
    int nn = t >> 3, k4 = (t & 7) * 4;
    float sc = (n0 + nn < slim) ? NRM : 1.0f;
    ushort4 o;
    o.x = f2bf(tl[k4 + 0][nn] * sc); o.y = f2bf(tl[k4 + 1][nn] * sc);
    o.z = f2bf(tl[k4 + 2][nn] * sc); o.w = f2bf(tl[k4 + 3][nn] * sc);
    *reinterpret_cast<ushort4*>(&out[(size_t)(n0 + nn) * Kd + k0 + k4]) = o;
}

// ---------------- LayerNorm -> bf16 ----------------
__global__ __launch_bounds__(256) void ln_kernel(const float* __restrict__ in,
                                                 const float* __restrict__ g,
                                                 const float* __restrict__ bb,
                                                 unsigned short* __restrict__ out) {
    int wave = threadIdx.x >> 6, lane = threadIdx.x & 63;
    long row = (long)blockIdx.x * 4 + wave;
    float4 v = reinterpret_cast<const float4*>(in + row * D)[lane];
    float s = v.x + v.y + v.z + v.w;
#pragma unroll
    for (int o = 32; o >= 1; o >>= 1) s += __shfl_xor(s, o);
    float mu = s * (1.0f / D);
    float d0 = v.x - mu, d1 = v.y - mu, d2 = v.z - mu, d3 = v.w - mu;
    float ss = d0 * d0 + d1 * d1 + d2 * d2 + d3 * d3;
#pragma unroll
    for (int o = 32; o >= 1; o >>= 1) ss += __shfl_xor(ss, o);
    float inv = rsqrtf(ss * (1.0f / D) + 1e-6f);
    float4 gv = reinterpret_cast<const float4*>(g)[lane];
    float4 bv = reinterpret_cast<const float4*>(bb)[lane];
    ushort4 o4;
    o4.x = f2bf(d0 * inv * gv.x + bv.x);
    o4.y = f2bf(d1 * inv * gv.y + bv.y);
    o4.z = f2bf(d2 * inv * gv.z + bv.z);
    o4.w = f2bf(d3 * inv * gv.w + bv.w);
    *reinterpret_cast<ushort4*>(&out[row * D + lane * 4]) = o4;
}

// ---------------- bf16 MFMA GEMM: out = A(MxK) @ Bt(NxK)^T ----------------
// operand-swapped MFMA so reg-dim = N -> vectorized epilogue stores.
template <bool BIAS, bool GELU_ACT, bool RESID, bool OUT16>
__global__ __launch_bounds__(256) void mgemm_kernel(const unsigned short* __restrict__ A,
                                                    const unsigned short* __restrict__ Bt,
                                                    const float* __restrict__ bias,
                                                    float* __restrict__ C,
                                                    unsigned short* __restrict__ O16,
                                                    int K, int Nc) {
    __shared__ short Als[128][32];
    __shared__ short Bls[128][32];
    int t = threadIdx.x;
    int l = t & 63, w = t >> 6;
    int wr = w >> 1, wc = w & 1;
    long m0 = (long)blockIdx.y * 128;
    int n0 = blockIdx.x * 128;
    int lr = l & 15;
    int lg = l >> 4;
    int kp8 = lg * 8;
    int srow = t >> 2, skoff = (t & 3) * 8;

    f32x4 acc[4][4];
#pragma unroll
    for (int i = 0; i < 4; i++)
#pragma unroll
        for (int j = 0; j < 4; j++) acc[i][j] = (f32x4){0.f, 0.f, 0.f, 0.f};

    for (int k0 = 0; k0 < K; k0 += 32) {
#pragma unroll
        for (int it = 0; it < 2; it++) {
            int r = srow + it * 64;
            short8 va = *reinterpret_cast<const short8*>(&A[(size_t)(m0 + r) * K + k0 + skoff]);
            *reinterpret_cast<short8*>(&Als[r][skoff]) = va;
            short8 vb = *reinterpret_cast<const short8*>(&Bt[(size_t)(n0 + r) * K + k0 + skoff]);
            *reinterpret_cast<short8*>(&Bls[r][skoff]) = vb;
        }
        __syncthreads();
        short8 a[4], b[4];
#pragma unroll
        for (int i = 0; i < 4; i++)
            a[i] = *reinterpret_cast<const short8*>(&Als[wr * 64 + i * 16 + lr][kp8]);
#pragma unroll
        for (int j = 0; j < 4; j++)
            b[j] = *reinterpret_cast<const short8*>(&Bls[wc * 64 + j * 16 + lr][kp8]);
#pragma unroll
        for (int i = 0; i < 4; i++)
#pragma unroll
            for (int j = 0; j < 4; j++)   // swapped: reg-dim = n
                acc[i][j] = __builtin_amdgcn_mfma_f32_16x16x32_bf16(b[j], a[i], acc[i][j], 0, 0, 0);
        __syncthreads();
    }

    float4 bias4[4];
    if (BIAS) {
#pragma unroll
        for (int j = 0; j < 4; j++)
            bias4[j] = *reinterpret_cast<const float4*>(&bias[n0 + wc * 64 + j * 16 + lg * 4]);
    }
#pragma unroll
    for (int i = 0; i < 4; i++) {
        long grow = m0 + wr * 64 + i * 16 + lr;
#pragma unroll
        for (int j = 0; j < 4; j++) {
            int gcol = n0 + wc * 64 + j * 16 + lg * 4;
            f32x4 v = acc[i][j];
            if (BIAS) {
                v[0] += bias4[j].x; v[1] += bias4[j].y; v[2] += bias4[j].z; v[3] += bias4[j].w;
            }
            if (GELU_ACT) {
#pragma unroll
                for (int r = 0; r < 4; r++)
                    v[r] = 0.5f * v[r] * (1.0f + erff(v[r] * 0.70710678118654752f));
            }
            if (OUT16) {
                short4 o;
                o.x = (short)f2bf(v[0]); o.y = (short)f2bf(v[1]);
                o.z = (short)f2bf(v[2]); o.w = (short)f2bf(v[3]);
                *reinterpret_cast<short4*>(&O16[grow * Nc + gcol]) = o;
            } else if (RESID) {
                float4 c0 = *reinterpret_cast<const float4*>(&C[grow * Nc + gcol]);
                c0.x += v[0]; c0.y += v[1]; c0.z += v[2]; c0.w += v[3];
                *reinterpret_cast<float4*>(&C[grow * Nc + gcol]) = c0;
            } else {
                float4 c0 = {v[0], v[1], v[2], v[3]};
                *reinterpret_cast<float4*>(&C[grow * Nc + gcol]) = c0;
            }
        }
    }
}

// ---------------- kv: MFMA u + online-max + MFMA kp^T @ v, partials ----------------
#define KV_P 8
#define KV_ROWS (N / KV_P)      // 512
#define PSZ 8484                // 8192 acc + 256 asum + 32 vsum + 1 Lm + pad
__global__ __launch_bounds__(256) void kv_kernel(const unsigned short* __restrict__ qkv16,
                                                 const unsigned short* __restrict__ projbf,
                                                 float* __restrict__ kvp) {
    __shared__ __align__(16) unsigned short kp_sT[256][72];   // [m][n-chunk]
    __shared__ __align__(16) unsigned short vT_s[32][72];     // [d][n-chunk]
    __shared__ float red[4];
    __shared__ float asumred[4][256];
    __shared__ float vred[256][4];
    int t = threadIdx.x;
    int l = t & 63, w = t >> 6;
    int lr = l & 15, lg = l >> 4;
    int bh = blockIdx.x, b = bh >> 3, h = bh & 7;
    int n0 = blockIdx.y * KV_ROWS;

    f32x4 kvacc[4][2];
#pragma unroll
    for (int mf = 0; mf < 4; mf++)
#pragma unroll
        for (int dd = 0; dd < 2; dd++) kvacc[mf][dd] = (f32x4){0.f, 0.f, 0.f, 0.f};
    float asum_p[16];
#pragma unroll
    for (int f = 0; f < 16; f++) asum_p[f] = 0.f;
    float4 vs4 = {0.f, 0.f, 0.f, 0.f};
    float Lm = -1e30f;

    for (int c = 0; c < KV_ROWS / 64; c++) {
        // ---- K rows (already *NRM, bf16) -> A-frag (+ dg) ----
        size_t kbase = ((size_t)(b * N) + n0 + c * 64 + w * 16 + lr) * 768 + 256 + h * 32 + lg * 8;
        short8 aq = *reinterpret_cast<const short8*>(qkv16 + kbase);
        float sq = 0.f;
#pragma unroll
        for (int e = 0; e < 8; e++) {
            float xx = bfu2f((unsigned short)aq[e]);
            sq += xx * xx;
        }
        sq += __shfl_xor(sq, 16);
        sq += __shfl_xor(sq, 32);
        // ---- u = k @ projT via mfma ----
        f32x4 ua[16];
#pragma unroll
        for (int f = 0; f < 16; f++) {
            short8 bq = *reinterpret_cast<const short8*>(projbf + (f * 16 + lr) * 32 + lg * 8);
            ua[f] = __builtin_amdgcn_mfma_f32_16x16x32_bf16(aq, bq, (f32x4){0.f, 0.f, 0.f, 0.f}, 0, 0, 0);
        }
        // ---- chunk max (block-wide) ----
        float cm = -1e30f;
#pragma unroll
        for (int f = 0; f < 16; f++)
#pragma unroll
            for (int r = 0; r < 4; r++) cm = fmaxf(cm, ua[f][r]);
#pragma unroll
        for (int o = 1; o < 64; o <<= 1) cm = fmaxf(cm, __shfl_xor(cm, o));
        if (l == 0) red[w] = cm;
        __syncthreads();
        float bm = fmaxf(fmaxf(red[0], red[1]), fmaxf(red[2], red[3]));
        if (bm > Lm) {
            float sc = __expf(Lm - bm);
#pragma unroll
            for (int mf = 0; mf < 4; mf++)
#pragma unroll
                for (int dd = 0; dd < 2; dd++) {
                    kvacc[mf][dd][0] *= sc; kvacc[mf][dd][1] *= sc;
                    kvacc[mf][dd][2] *= sc; kvacc[mf][dd][3] *= sc;
                }
#pragma unroll
            for (int f = 0; f < 16; f++) asum_p[f] *= sc;
            Lm = bm;
        }
        float dgr[4];
#pragma unroll
        for (int r = 0; r < 4; r++) dgr[r] = 0.5f * __shfl(sq, lg * 4 + r);
        // ---- kp = exp(u - dg - Lm) -> LDS transposed ----
#pragma unroll
        for (int f = 0; f < 16; f++) {
#pragma unroll
            for (int r = 0; r < 4; r++) {
                float p = __expf(ua[f][r] - dgr[r] - Lm);
                asum_p[f] += p;
                kp_sT[f * 16 + lr][w * 16 + lg * 4 + r] = f2bf(p);
            }
        }
        // ---- stage v^T (bf16, direct) ----
#pragma unroll
        for (int ii = 0; ii < 2; ii++) {
            int idx = t + ii * 256;
            int nn = idx >> 3, dz = (idx & 7) * 4;
            const unsigned short* vp =
                qkv16 + ((size_t)(b * N) + n0 + c * 64 + nn) * 768 + 512 + h * 32 + dz;
            short4 vv = *reinterpret_cast<const short4*>(vp);
            float v0 = bfu2f((unsigned short)vv.x), v1 = bfu2f((unsigned short)vv.y);
            float v2 = bfu2f((unsigned short)vv.z), v3 = bfu2f((unsigned short)vv.w);
            vs4.x += v0; vs4.y += v1; vs4.z += v2; vs4.w += v3;
            vT_s[dz + 0][nn] = (unsigned short)vv.x; vT_s[dz + 1][nn] = (unsigned short)vv.y;
            vT_s[dz + 2][nn] = (unsigned short)vv.z; vT_s[dz + 3][nn] = (unsigned short)vv.w;
        }
        __syncthreads();
        // ---- kv += kp^T @ v ----
#pragma unroll
        for (int ks = 0; ks < 2; ks++) {
            short8 bv0 = *reinterpret_cast<const short8*>(&vT_s[lr][ks * 32 + lg * 8]);
            short8 bv1 = *reinterpret_cast<const short8*>(&vT_s[16 + lr][ks * 32 + lg * 8]);
#pragma unroll
            for (int mf = 0; mf < 4; mf++) {
                short8 am = *reinterpret_cast<const short8*>(&kp_sT[w * 64 + mf * 16 + lr][ks * 32 + lg * 8]);
                kvacc[mf][0] = __builtin_amdgcn_mfma_f32_16x16x32_bf16(am, bv0, kvacc[mf][0], 0, 0, 0);
                kvacc[mf][1] = __builtin_amdgcn_mfma_f32_16x16x32_bf16(am, bv1, kvacc[mf][1], 0, 0, 0);
            }
        }
    }
    // ---- asum wave reduce + stores ----
#pragma unroll
    for (int f = 0; f < 16; f++) {
        asum_p[f] += __shfl_xor(asum_p[f], 16);
        asum_p[f] += __shfl_xor(asum_p[f], 32);
    }
    if (l < 16) {
#pragma unroll
        for (int f = 0; f < 16; f++) asumred[w][f * 16 + l] = asum_p[f];
    }
    vred[t][0] = vs4.x; vred[t][1] = vs4.y; vred[t][2] = vs4.z; vred[t][3] = vs4.w;
    __syncthreads();
    size_t base = ((size_t)bh * KV_P + blockIdx.y) * PSZ;
#pragma unroll
    for (int mf = 0; mf < 4; mf++)
#pragma unroll
        for (int dd = 0; dd < 2; dd++)
#pragma unroll
            for (int r = 0; r < 4; r++) {
                int m = w * 64 + mf * 16 + lg * 4 + r;
                int d = dd * 16 + lr;
                kvp[base + m * 32 + d] = kvacc[mf][dd][r];
            }
    {
        float s = asumred[0][t] + asumred[1][t] + asumred[2][t] + asumred[3][t];
        kvp[base + 8192 + t] = s;
    }
    if (t < 32) {
        int f4g = t >> 2, cc = t & 3;
        float s = 0.f;
#pragma unroll
        for (int g = 0; g < 32; g++) s += vred[g * 8 + f4g][cc];
        kvp[base + 8448 + t] = s;
    }
    if (t == 0) kvp[base + 8480] = Lm;
}

// ---------------- combine partials -> kvT bf16, ksum ----------------
__global__ __launch_bounds__(256) void kv_combine_kernel(const float* __restrict__ kvp,
                                                         unsigned short* __restrict__ kvTb,
                                                         float* __restrict__ ksumf) {
    __shared__ float vst[32];
    int t = threadIdx.x;
    int bh = blockIdx.x;
    size_t base0 = (size_t)bh * KV_P * PSZ;
    float Lp[KV_P];
    float gm = -1e30f;
#pragma unroll
    for (int p = 0; p < KV_P; p++) {
        Lp[p] = kvp[base0 + p * PSZ + 8480];
        gm = fmaxf(gm, Lp[p]);
    }
    if (t < 32) {
        float s = 0.f;
#pragma unroll
        for (int p = 0; p < KV_P; p++) s += kvp[base0 + p * PSZ + 8448 + t];
        vst[t] = s;
    }
    __syncthreads();
    float4 av[8];
#pragma unroll
    for (int d4 = 0; d4 < 8; d4++) av[d4] = (float4){0.f, 0.f, 0.f, 0.f};
    float S = 0.f;
#pragma unroll
    for (int p = 0; p < KV_P; p++) {
        float e = __expf(Lp[p] - gm);
        size_t pb = base0 + p * PSZ;
#pragma unroll
        for (int d4 = 0; d4 < 8; d4++) {
            float4 a = *reinterpret_cast<const float4*>(&kvp[pb + t * 32 + d4 * 4]);
            av[d4].x += e * a.x; av[d4].y += e * a.y; av[d4].z += e * a.z; av[d4].w += e * a.w;
        }
        S += e * kvp[pb + 8192 + t];
    }
#pragma unroll
    for (int d4 = 0; d4 < 8; d4++) {
        float o0 = (av[d4].x + 1e-4f * vst[d4 * 4 + 0]) * 0.0625f;
        float o1 = (av[d4].y + 1e-4f * vst[d4 * 4 + 1]) * 0.0625f;
        float o2 = (av[d4].z + 1e-4f * vst[d4 * 4 + 2]) * 0.0625f;
        float o3 = (av[d4].w + 1e-4f * vst[d4 * 4 + 3]) * 0.0625f;
        kvTb[((size_t)bh * 32 + d4 * 4 + 0) * 256 + t] = f2bf(o0);
        kvTb[((size_t)bh * 32 + d4 * 4 + 1) * 256 + t] = f2bf(o1);
        kvTb[((size_t)bh * 32 + d4 * 4 + 2) * 256 + t] = f2bf(o2);
        kvTb[((size_t)bh * 32 + d4 * 4 + 3) * 256 + t] = f2bf(o3);
    }
    ksumf[bh * 256 + t] = (S + 1e-4f * (float)N) * 0.0625f;
}

// ---------------- q-side fused attention (swapped-operand MFMA) ----------------
// u-MFMA: mfma(proj, q) -> lane holds qp[q-row = lane&15][m = f*16+lg*4+r]
// PV:     mfma(kv, qp)  -> reg-dim = d -> short4 stores
__global__ __launch_bounds__(256) void attn_kernel(const unsigned short* __restrict__ qkv16,
                                                   const unsigned short* __restrict__ projbf,
                                                   const unsigned short* __restrict__ kvTb,
                                                   const float* __restrict__ ksumf,
                                                   unsigned short* __restrict__ attn16) {
    __shared__ __align__(16) unsigned short qp_s[64][264];
    __shared__ float ksumL[256];
    int t = threadIdx.x;
    int l = t & 63, w = t >> 6;
    int lr = l & 15, lg = l >> 4;
    int bh = blockIdx.x, b = bh >> 3, h = bh & 7;
    int n0 = blockIdx.y * 64;

    ksumL[t] = ksumf[bh * 256 + t];
    __syncthreads();

    // ---- q B-frag (already *NRM, bf16) + dg ----
    size_t qbase = ((size_t)(b * N) + n0 + w * 16 + lr) * 768 + h * 32 + lg * 8;
    short8 qf = *reinterpret_cast<const short8*>(qkv16 + qbase);
    float sq = 0.f;
#pragma unroll
    for (int e = 0; e < 8; e++) {
        float xx = bfu2f((unsigned short)qf[e]);
        sq += xx * xx;
    }
    sq += __shfl_xor(sq, 16);
    sq += __shfl_xor(sq, 32);
    float dg = 0.5f * sq;      // for q-row lr

    // ---- u = proj x q (swapped) ----
    f32x4 ua[16];
#pragma unroll
    for (int f = 0; f < 16; f++) {
        short8 bq = *reinterpret_cast<const short8*>(projbf + (f * 16 + lr) * 32 + lg * 8);
        ua[f] = __builtin_amdgcn_mfma_f32_16x16x32_bf16(bq, qf, (f32x4){0.f, 0.f, 0.f, 0.f}, 0, 0, 0);
    }

    // ---- rowmax over m (local 64 then cross-lg) ----
    float mx = -1e30f;
#pragma unroll
    for (int f = 0; f < 16; f++)
#pragma unroll
        for (int r = 0; r < 4; r++) mx = fmaxf(mx, ua[f][r]);
    mx = fmaxf(mx, __shfl_xor(mx, 16));
    mx = fmaxf(mx, __shfl_xor(mx, 32));

    // ---- qp, z ----
    float zs = 0.f;
#pragma unroll
    for (int f = 0; f < 16; f++) {
        float4 ks4 = *reinterpret_cast<const float4*>(&ksumL[f * 16 + lg * 4]);
        float p0 = (__expf(ua[f][0] - dg - mx) + 1e-4f) * 0.0625f;
        float p1 = (__expf(ua[f][1] - dg - mx) + 1e-4f) * 0.0625f;
        float p2 = (__expf(ua[f][2] - dg - mx) + 1e-4f) * 0.0625f;
        float p3 = (__expf(ua[f][3] - dg - mx) + 1e-4f) * 0.0625f;
        zs += p0 * ks4.x + p1 * ks4.y + p2 * ks4.z + p3 * ks4.w;
        short4 o;
        o.x = (short)f2bf(p0); o.y = (short)f2bf(p1);
        o.z = (short)f2bf(p2); o.w = (short)f2bf(p3);
        *reinterpret_cast<short4*>(&qp_s[w * 16 + lr][f * 16 + lg * 4]) = o;
    }
    zs += __shfl_xor(zs, 16);
    zs += __shfl_xor(zs, 32);
    float zf = 1.0f / (zs + 1e-6f);   // for q-row lr
    __syncthreads();

    // ---- out = kv x qp (swapped: reg-dim = d) ----
    f32x4 oacc[2];
    oacc[0] = (f32x4){0.f, 0.f, 0.f, 0.f};
    oacc[1] = (f32x4){0.f, 0.f, 0.f, 0.f};
    const unsigned short* kvb = kvTb + (size_t)bh * 32 * 256;
#pragma unroll
    for (int k0 = 0; k0 < 8; k0++) {
        short8 qpf = *reinterpret_cast<const short8*>(&qp_s[w * 16 + lr][k0 * 32 + lg * 8]);
        short8 a0 = *reinterpret_cast<const short8*>(kvb + (size_t)lr * 256 + k0 * 32 + lg * 8);
        short8 a1 = *reinterpret_cast<const short8*>(kvb + (size_t)(16 + lr) * 256 + k0 * 32 + lg * 8);
        oacc[0] = __builtin_amdgcn_mfma_f32_16x16x32_bf16(a0, qpf, oacc[0], 0, 0, 0);
        oacc[1] = __builtin_amdgcn_mfma_f32_16x16x32_bf16(a1, qpf, oacc[1], 0, 0, 0);
    }
    size_t orow = ((size_t)(b * N) + n0 + w * 16 + lr) * 256 + h * 32;
#pragma unroll
    for (int dd = 0; dd < 2; dd++) {
        short4 o;
        o.x = (short)f2bf(oacc[dd][0] * zf);
        o.y = (short)f2bf(oacc[dd][1] * zf);
        o.z = (short)f2bf(oacc[dd][2] * zf);
        o.w = (short)f2bf(oacc[dd][3] * zf);
        *reinterpret_cast<short4*>(&attn16[orow + dd * 16 + lg * 4]) = o;
    }
}

extern "C" void kernel_launch(void* const* d_in, const int* in_sizes, int n_in,
                              void* d_out, int out_size, void* d_ws, size_t ws_size,
                              hipStream_t stream) {
    const float* x = (const float*)d_in[0];
    const float* pos = (const float*)d_in[1];
    const float* g1 = (const float*)d_in[2];
    const float* b1 = (const float*)d_in[3];
    const float* g2 = (const float*)d_in[4];
    const float* b2 = (const float*)d_in[5];
    const float* Wqkv = (const float*)d_in[6];
    const float* Wproj = (const float*)d_in[7];
    const float* bproj = (const float*)d_in[8];
    const float* W1 = (const float*)d_in[9];
    const float* b1m = (const float*)d_in[10];
    const float* W2 = (const float*)d_in[11];
    const float* b2m = (const float*)d_in[12];
    const float* projm = (const float*)d_in[13];

    float* h = (float*)d_out;
    char* p = (char*)d_ws;
    auto alloc = [&](size_t bytes) { char* r = p; p += (bytes + 255) & ~(size_t)255; return r; };
    unsigned short* wbf    = (unsigned short*)alloc((size_t)DEPTH * 786432 * 2);
    unsigned short* projb  = (unsigned short*)alloc((size_t)DEPTH * M * DH * 2);
    unsigned short* ln16   = (unsigned short*)alloc((size_t)B * N * D * 2);
    unsigned short* qkv16  = (unsigned short*)alloc((size_t)B * N * HID * 2);  // union w/ hid16
    unsigned short* hid16  = qkv16;
    unsigned short* attn16 = (unsigned short*)alloc((size_t)B * N * D * 2);
    float* kvp             = (float*)alloc((size_t)64 * KV_P * PSZ * 4);
    unsigned short* kvTb   = (unsigned short*)alloc((size_t)64 * 32 * 256 * 2);
    float* ksumf           = (float*)alloc((size_t)64 * 256 * 4);

    // ---- weight prep (NRM folded into q,k cols of Wqkv) ----
    for (int l = 0; l < DEPTH; l++) {
        size_t lb = (size_t)l * 786432;
        wtrans_kernel<<<dim3(768 / 32, 256 / 32), 256, 0, stream>>>(
            Wqkv + (size_t)l * D * 3 * D, wbf + lb + 0, 256, 768, 512);
        wtrans_kernel<<<dim3(256 / 32, 256 / 32), 256, 0, stream>>>(
            Wproj + (size_t)l * D * D, wbf + lb + 196608, 256, 256, 0);
        wtrans_kernel<<<dim3(1024 / 32, 256 / 32), 256, 0, stream>>>(
            W1 + (size_t)l * D * HID, wbf + lb + 262144, 256, 1024, 0);
        wtrans_kernel<<<dim3(256 / 32, 1024 / 32), 256, 0, stream>>>(
            W2 + (size_t)l * HID * D, wbf + lb + 524288, 1024, 256, 0);
    }
    projbf_kernel<<<DEPTH * M * DH / 256, 256, 0, stream>>>(projm, projb);

    add_pos_kernel<<<B * N * D / 256, 256, 0, stream>>>(x, pos, h);

    for (int l = 0; l < DEPTH; l++) {
        size_t lb = (size_t)l * 786432;
        const unsigned short* wqT = wbf + lb + 0;
        const unsigned short* wpT = wbf + lb + 196608;
        const unsigned short* w1T = wbf + lb + 262144;
        const unsigned short* w2T = wbf + lb + 524288;
        const float* bp = bproj + (size_t)l * D;
        const float* b1l = b1m + (size_t)l * HID;
        const float* b2l = b2m + (size_t)l * D;
        const unsigned short* prb = projb + (size_t)l * M * DH;

        ln_kernel<<<B * N / 4, 256, 0, stream>>>(h, g1, b1, ln16);
        mgemm_kernel<false, false, false, true><<<dim3(768 / 128, B * N / 128), 256, 0, stream>>>(
            ln16, wqT, nullptr, nullptr, qkv16, 256, 768);
        kv_kernel<<<dim3(B * H, KV_P), 256, 0, stream>>>(qkv16, prb, kvp);
        kv_combine_kernel<<<B * H, 256, 0, stream>>>(kvp, kvTb, ksumf);
        attn_kernel<<<dim3(B * H, N / 64), 256, 0, stream>>>(qkv16, prb, kvTb, ksumf, attn16);
        mgemm_kernel<true, false, true, false><<<dim3(256 / 128, B * N / 128), 256, 0, stream>>>(
            attn16, wpT, bp, h, nullptr, 256, 256);
        ln_kernel<<<B * N / 4, 256, 0, stream>>>(h, g2, b2, ln16);
        mgemm_kernel<true, true, false, true><<<dim3(1024 / 128, B * N / 128), 256, 0, stream>>>(
            ln16, w1T, b1l, nullptr, hid16, 256, 1024);
        mgemm_kernel<true, false, true, false><<<dim3(256 / 128, B * N / 128), 256, 0, stream>>>(
            hid16, w2T, b2l, h, nullptr, 1024, 256);
    }
}